// Round 3
// baseline (1192.389 us; speedup 1.0000x reference)
//
#include <hip/hip_runtime.h>
#include <hip/hip_bf16.h>
#include <cstdint>
#include <cstddef>

using bf16 = __hip_bfloat16;
typedef __attribute__((ext_vector_type(8))) short bf16x8;
typedef __attribute__((ext_vector_type(4))) float floatx4;

#define GLOBAL_AS __attribute__((address_space(1)))
#define LDS_AS    __attribute__((address_space(3)))

__device__ __forceinline__ void async_copy16(void* lds, const void* g) {
    __builtin_amdgcn_global_load_lds((GLOBAL_AS void*)(g), (LDS_AS void*)(lds), 16, 0, 0);
}

__device__ __forceinline__ floatx4 mfma_bf16(bf16x8 a, bf16x8 b, floatx4 c) {
    return __builtin_amdgcn_mfma_f32_16x16x32_bf16(a, b, c, 0, 0, 0);
}

// fp32 -> bf16 elementwise, 4 elements/thread. n must be a multiple of 4.
__global__ void cvt_f32_bf16(const float* __restrict__ src, bf16* __restrict__ dst, int n) {
    int i = (blockIdx.x * blockDim.x + threadIdx.x) * 4;
    if (i < n) {
        float4 v = *(const float4*)(src + i);
        __align__(8) bf16 t[4];
        t[0] = __float2bfloat16(v.x);
        t[1] = __float2bfloat16(v.y);
        t[2] = __float2bfloat16(v.z);
        t[3] = __float2bfloat16(v.w);
        *(short4*)(dst + i) = *(const short4*)t;
    }
}

// C[m,n] = sum_k A[m,k] * W[n,k] + bias[n].   (bias is fp32)
// OUTF==0: C bf16 [M][N] row-major; OUTF==1: C fp32 [M][N] row-major.
template <int OUTF>
__global__ __launch_bounds__(256, 3) void gemm_bt_bias(
    const bf16* __restrict__ A, const bf16* __restrict__ W,
    const float* __restrict__ bias, void* __restrict__ Cv,
    int M, int N, int K)
{
    __shared__ __align__(16) bf16 As[128 * 32];
    __shared__ __align__(16) bf16 Ws[128 * 32];

    const int tid  = threadIdx.x;
    const int lane = tid & 63;
    const int wave = tid >> 6;
    const int quad = lane >> 4;
    const int l16  = lane & 15;
    const int wm = (wave >> 1) * 64;
    const int wn = (wave & 1) * 64;

    const int bm = blockIdx.x;
    const int bn = blockIdx.y;

    floatx4 acc[4][4];
#pragma unroll
    for (int i = 0; i < 4; ++i)
#pragma unroll
        for (int j = 0; j < 4; ++j) acc[i][j] = (floatx4){0.f, 0.f, 0.f, 0.f};

    const int srow = tid >> 2;
    const int scol = (tid & 3) * 8;
    const bf16* gA = A + (size_t)(bm * 128 + srow) * K + scol;
    const bf16* gW = W + (size_t)(bn * 128 + srow) * K + scol;
    bf16* lA0 = As + tid * 8;
    bf16* lA1 = As + 2048 + tid * 8;
    bf16* lW0 = Ws + tid * 8;
    bf16* lW1 = Ws + 2048 + tid * 8;
    const size_t skip = (size_t)64 * K;

    const int kt_n = K >> 5;
    for (int kt = 0; kt < kt_n; ++kt) {
        __syncthreads();
        const bf16* ga = gA + kt * 32;
        const bf16* gw = gW + kt * 32;
        async_copy16(lA0, ga);
        async_copy16(lA1, ga + skip);
        async_copy16(lW0, gw);
        async_copy16(lW1, gw + skip);
        __syncthreads();

        bf16x8 af[4], bfr[4];
#pragma unroll
        for (int mi = 0; mi < 4; ++mi)
            af[mi] = *(const bf16x8*)(As + (wm + mi * 16 + l16) * 32 + quad * 8);
#pragma unroll
        for (int ni = 0; ni < 4; ++ni)
            bfr[ni] = *(const bf16x8*)(Ws + (wn + ni * 16 + l16) * 32 + quad * 8);
#pragma unroll
        for (int mi = 0; mi < 4; ++mi)
#pragma unroll
            for (int ni = 0; ni < 4; ++ni)
                acc[mi][ni] = mfma_bf16(af[mi], bfr[ni], acc[mi][ni]);
    }

#pragma unroll
    for (int mi = 0; mi < 4; ++mi) {
        const int row0 = bm * 128 + wm + mi * 16 + quad * 4;
#pragma unroll
        for (int ni = 0; ni < 4; ++ni) {
            const int col = bn * 128 + wn + ni * 16 + l16;
            const float bv = bias[col];
            if (OUTF) {
                float* C = (float*)Cv;
#pragma unroll
                for (int r = 0; r < 4; ++r)
                    C[(size_t)(row0 + r) * N + col] = acc[mi][ni][r] + bv;
            } else {
                bf16* C = (bf16*)Cv;
#pragma unroll
                for (int r = 0; r < 4; ++r)
                    C[(size_t)(row0 + r) * N + col] = __float2bfloat16(acc[mi][ni][r] + bv);
            }
        }
    }
}

// Fused K+V projection. Logical N=2048: bn<8 -> K rows (k_buf row-major
// [M][1024] bf16); bn>=8 -> V rows (vt [B][1024][T] transposed bf16 store).
__global__ __launch_bounds__(256, 3) void gemm_kv(
    const bf16* __restrict__ A,
    const bf16* __restrict__ Wk, const bf16* __restrict__ Wv,
    const float* __restrict__ bk, const float* __restrict__ bv,
    bf16* __restrict__ kout, bf16* __restrict__ vt,
    int M, int K)
{
    __shared__ __align__(16) bf16 As[128 * 32];
    __shared__ __align__(16) bf16 Ws[128 * 32];

    const int tid  = threadIdx.x;
    const int lane = tid & 63;
    const int wave = tid >> 6;
    const int quad = lane >> 4;
    const int l16  = lane & 15;
    const int wm = (wave >> 1) * 64;
    const int wn = (wave & 1) * 64;

    const int bm = blockIdx.x;
    const int bn = blockIdx.y;
    const bool isK = (bn < 8);
    const int nb = isK ? bn : (bn - 8);             // 128-row tile within Wk/Wv
    const bf16* Wsel  = isK ? Wk : Wv;
    const float* bsel = isK ? bk : bv;

    floatx4 acc[4][4];
#pragma unroll
    for (int i = 0; i < 4; ++i)
#pragma unroll
        for (int j = 0; j < 4; ++j) acc[i][j] = (floatx4){0.f, 0.f, 0.f, 0.f};

    const int srow = tid >> 2;
    const int scol = (tid & 3) * 8;
    const bf16* gA = A    + (size_t)(bm * 128 + srow) * K + scol;
    const bf16* gW = Wsel + (size_t)(nb * 128 + srow) * K + scol;
    bf16* lA0 = As + tid * 8;
    bf16* lA1 = As + 2048 + tid * 8;
    bf16* lW0 = Ws + tid * 8;
    bf16* lW1 = Ws + 2048 + tid * 8;
    const size_t skip = (size_t)64 * K;

    const int kt_n = K >> 5;
    for (int kt = 0; kt < kt_n; ++kt) {
        __syncthreads();
        const bf16* ga = gA + kt * 32;
        const bf16* gw = gW + kt * 32;
        async_copy16(lA0, ga);
        async_copy16(lA1, ga + skip);
        async_copy16(lW0, gw);
        async_copy16(lW1, gw + skip);
        __syncthreads();

        bf16x8 af[4], bfr[4];
#pragma unroll
        for (int mi = 0; mi < 4; ++mi)
            af[mi] = *(const bf16x8*)(As + (wm + mi * 16 + l16) * 32 + quad * 8);
#pragma unroll
        for (int ni = 0; ni < 4; ++ni)
            bfr[ni] = *(const bf16x8*)(Ws + (wn + ni * 16 + l16) * 32 + quad * 8);
#pragma unroll
        for (int mi = 0; mi < 4; ++mi)
#pragma unroll
            for (int ni = 0; ni < 4; ++ni)
                acc[mi][ni] = mfma_bf16(af[mi], bfr[ni], acc[mi][ni]);
    }

#pragma unroll
    for (int mi = 0; mi < 4; ++mi) {
        const int row0 = bm * 128 + wm + mi * 16 + quad * 4;
#pragma unroll
        for (int ni = 0; ni < 4; ++ni) {
            const int col = nb * 128 + wn + ni * 16 + l16;   // 0..1023
            const float bvv = bsel[col];
            if (isK) {
#pragma unroll
                for (int r = 0; r < 4; ++r)
                    kout[(size_t)(row0 + r) * 1024 + col] = __float2bfloat16(acc[mi][ni][r] + bvv);
            } else {
                __align__(8) bf16 tmp[4];
#pragma unroll
                for (int r = 0; r < 4; ++r) tmp[r] = __float2bfloat16(acc[mi][ni][r] + bvv);
                const int b  = row0 >> 11;      // T = 2048
                const int t0 = row0 & 2047;
                bf16* dst = vt + ((size_t)(b * 1024 + col)) * 2048 + t0;
                *(short4*)dst = *(const short4*)tmp;
            }
        }
    }
}

// Flash attention, causal. q:[B*T][4096] col=h*128+d; k:[B*T][1024] col=g*128+d;
// vt:[B][1024][T] (transposed); o:[B*T][4096]. All bf16.
// Q fragments live in registers; K/V staged via register double-buffer so the
// global loads for tile st+1 are in flight during tile st's compute.
__global__ __launch_bounds__(256, 3) void attn_fwd(
    const bf16* __restrict__ qb, const bf16* __restrict__ kb,
    const bf16* __restrict__ vtb, bf16* __restrict__ ob)
{
    constexpr int T  = 2048;
    constexpr int DQ = 4096;
    constexpr int DK = 1024;

    __shared__ __align__(16) bf16 Ks[64][136];   // +8 pad
    __shared__ __align__(16) bf16 Vt[128][72];   // [d][s] +8 pad
    __shared__ __align__(16) bf16 Ps[4][16][72]; // per-wave P tile

    const int tid  = threadIdx.x;
    const int lane = tid & 63;
    const int wave = tid >> 6;
    const int quad = lane >> 4;
    const int l16  = lane & 15;

    const int qt = blockIdx.x;
    const int bh = blockIdx.y;
    const int b  = bh >> 5;
    const int h  = bh & 31;
    const int g  = h >> 2;        // GROUP = 4
    const int q0 = qt * 64;
    const int qw = wave * 16;

    const bf16* Qg = qb  + (size_t)b * T * DQ + (size_t)h * 128;
    const bf16* Kg = kb  + (size_t)b * T * DK + (size_t)g * 128;
    const bf16* Vg = vtb + ((size_t)b * DK + g * 128) * T;
    bf16*       Og = ob  + (size_t)b * T * DQ + (size_t)h * 128;

    // ---- Q fragments: loop-invariant, straight to registers ----
    bf16x8 qf[4];
#pragma unroll
    for (int kk = 0; kk < 4; ++kk)
        qf[kk] = *(const bf16x8*)(Qg + (size_t)(q0 + qw + l16) * DQ + kk * 32 + quad * 8);

    // ---- K/V staging addresses (per thread) ----
    const int kr = tid >> 4, kc = (tid & 15) * 8;   // K: [64][128], 4 chunks of 16 rows
    const int vr = tid >> 3, vc = (tid & 7) * 8;    // V: [128][64], 4 chunks of 32 rows
    const bf16* kbase = Kg + (size_t)kr * DK + kc;
    const bf16* vbase = Vg + (size_t)vr * T + vc;

    int4 kreg[4], vreg[4];
#pragma unroll
    for (int it = 0; it < 4; ++it) {
        kreg[it] = *(const int4*)(kbase + (size_t)(it * 16) * DK);
        vreg[it] = *(const int4*)(vbase + (size_t)(it * 32) * T);
    }

    floatx4 oacc[8];
#pragma unroll
    for (int i = 0; i < 8; ++i) oacc[i] = (floatx4){0.f, 0.f, 0.f, 0.f};
    float m_run[4], l_run[4];
#pragma unroll
    for (int r = 0; r < 4; ++r) { m_run[r] = -1e30f; l_run[r] = 0.f; }

    const float scale = 0.08838834764831845f;  // 1/sqrt(128)

    for (int st = 0; st <= qt; ++st) {
        __syncthreads();  // previous tile's LDS reads done
#pragma unroll
        for (int it = 0; it < 4; ++it) {
            *(int4*)&Ks[kr + it * 16][kc] = kreg[it];
            *(int4*)&Vt[vr + it * 32][vc] = vreg[it];
        }
        __syncthreads();  // staged K/V visible

        // prefetch next tile while computing this one
        if (st < qt) {
            const int sn = (st + 1) * 64;
#pragma unroll
            for (int it = 0; it < 4; ++it) {
                kreg[it] = *(const int4*)(kbase + (size_t)(sn + it * 16) * DK);
                vreg[it] = *(const int4*)(vbase + (size_t)(it * 32) * T + sn);
            }
        }

        const int s0 = st * 64;

        // S[16q][64s] per wave
        floatx4 sacc[4];
#pragma unroll
        for (int i = 0; i < 4; ++i) sacc[i] = (floatx4){0.f, 0.f, 0.f, 0.f};
#pragma unroll
        for (int kk = 0; kk < 4; ++kk) {
#pragma unroll
            for (int ni = 0; ni < 4; ++ni) {
                bf16x8 bk8 = *(const bf16x8*)&Ks[ni * 16 + l16][kk * 32 + quad * 8];
                sacc[ni] = mfma_bf16(qf[kk], bk8, sacc[ni]);
            }
        }

        const bool diag = (st == qt);
#pragma unroll
        for (int r = 0; r < 4; ++r) {
            const int qg = q0 + qw + quad * 4 + r;   // C/D row = quad*4+reg
            float sv[4];
#pragma unroll
            for (int ni = 0; ni < 4; ++ni) {
                float x = sacc[ni][r] * scale;
                if (diag && (s0 + ni * 16 + l16) > qg) x = -1e30f;
                sv[ni] = x;
            }
            float mx = fmaxf(fmaxf(sv[0], sv[1]), fmaxf(sv[2], sv[3]));
            mx = fmaxf(mx, __shfl_xor(mx, 1, 64));
            mx = fmaxf(mx, __shfl_xor(mx, 2, 64));
            mx = fmaxf(mx, __shfl_xor(mx, 4, 64));
            mx = fmaxf(mx, __shfl_xor(mx, 8, 64));
            const float mnew  = fmaxf(m_run[r], mx);
            const float alpha = __expf(m_run[r] - mnew);
            float ssum = 0.f;
#pragma unroll
            for (int ni = 0; ni < 4; ++ni) {
                float p = __expf(sv[ni] - mnew);
                ssum += p;
                Ps[wave][quad * 4 + r][ni * 16 + l16] = __float2bfloat16(p);
            }
            ssum += __shfl_xor(ssum, 1, 64);
            ssum += __shfl_xor(ssum, 2, 64);
            ssum += __shfl_xor(ssum, 4, 64);
            ssum += __shfl_xor(ssum, 8, 64);
            l_run[r] = l_run[r] * alpha + ssum;
            m_run[r] = mnew;
#pragma unroll
            for (int db = 0; db < 8; ++db) oacc[db][r] *= alpha;
        }
        asm volatile("s_waitcnt lgkmcnt(0)" ::: "memory");  // Ps visible wave-wide

        // O += P @ V
#pragma unroll
        for (int kk = 0; kk < 2; ++kk) {
            bf16x8 ap = *(const bf16x8*)&Ps[wave][l16][kk * 32 + quad * 8];
#pragma unroll
            for (int db = 0; db < 8; ++db) {
                bf16x8 bv8 = *(const bf16x8*)&Vt[db * 16 + l16][kk * 32 + quad * 8];
                oacc[db] = mfma_bf16(ap, bv8, oacc[db]);
            }
        }
    }

#pragma unroll
    for (int r = 0; r < 4; ++r) {
        const float inv = 1.0f / l_run[r];
        const int qg = q0 + qw + quad * 4 + r;
#pragma unroll
        for (int db = 0; db < 8; ++db)
            Og[(size_t)qg * DQ + db * 16 + l16] = __float2bfloat16(oacc[db][r] * inv);
    }
}

extern "C" void kernel_launch(void* const* d_in, const int* in_sizes, int n_in,
                              void* d_out, int out_size, void* d_ws, size_t ws_size,
                              hipStream_t stream)
{
    const float* hs = (const float*)d_in[0];
    const float* Wq = (const float*)d_in[1];
    const float* bq = (const float*)d_in[2];
    const float* Wk = (const float*)d_in[3];
    const float* bk = (const float*)d_in[4];
    const float* Wv = (const float*)d_in[5];
    const float* bv = (const float*)d_in[6];
    const float* Wo = (const float*)d_in[7];
    const float* bo = (const float*)d_in[8];
    float* out = (float*)d_out;

    const int M  = 4096;         // B*T tokens
    const int D  = 4096;
    const int DK = 1024;         // G*d
    const size_t SZ_D  = (size_t)M * D;
    const size_t SZ_K  = (size_t)M * DK;

    bf16* hsb  = (bf16*)d_ws;            // [M][D]
    bf16* Wqb  = hsb  + SZ_D;            // [D][D]
    bf16* Wkb  = Wqb  + SZ_D;            // [DK][D]
    bf16* Wvb  = Wkb  + SZ_K;            // [DK][D]
    bf16* Wob  = Wvb  + SZ_K;            // [D][D]
    bf16* q_buf = Wob + SZ_D;            // [M][D]
    bf16* k_buf = q_buf + SZ_D;          // [M][DK]
    bf16* vt_buf = Wqb;                  // ALIAS: Wq consumed before KV-gemm writes vt
    bf16* o_buf  = hsb;                  // ALIAS: hs consumed before attn writes o

    dim3 blk(256);
    const int CB = 256;
    cvt_f32_bf16<<<(int)(SZ_D / 4 + CB - 1) / CB, CB, 0, stream>>>(hs, hsb, (int)SZ_D);
    cvt_f32_bf16<<<(int)(SZ_D / 4 + CB - 1) / CB, CB, 0, stream>>>(Wq, Wqb, (int)SZ_D);
    cvt_f32_bf16<<<(int)(SZ_K / 4 + CB - 1) / CB, CB, 0, stream>>>(Wk, Wkb, (int)SZ_K);
    cvt_f32_bf16<<<(int)(SZ_K / 4 + CB - 1) / CB, CB, 0, stream>>>(Wv, Wvb, (int)SZ_K);
    cvt_f32_bf16<<<(int)(SZ_D / 4 + CB - 1) / CB, CB, 0, stream>>>(Wo, Wob, (int)SZ_D);

    gemm_bt_bias<0><<<dim3(M / 128, D / 128), blk, 0, stream>>>(hsb, Wqb, bq, q_buf, M, D, D);
    gemm_kv<<<dim3(M / 128, 16), blk, 0, stream>>>(hsb, Wkb, Wvb, bk, bv, k_buf, vt_buf, M, D);
    attn_fwd<<<dim3(32, 64), blk, 0, stream>>>(q_buf, k_buf, vt_buf, o_buf);
    gemm_bt_bias<1><<<dim3(M / 128, D / 128), blk, 0, stream>>>(o_buf, Wob, bo, out, M, D, D);
}

// Round 4
// 817.491 us; speedup vs baseline: 1.4586x; 1.4586x over previous
//
#include <hip/hip_runtime.h>
#include <hip/hip_bf16.h>
#include <cstdint>
#include <cstddef>

using bf16 = __hip_bfloat16;
typedef __attribute__((ext_vector_type(8))) short bf16x8;
typedef __attribute__((ext_vector_type(4))) float floatx4;

#define GLOBAL_AS __attribute__((address_space(1)))
#define LDS_AS    __attribute__((address_space(3)))

__device__ __forceinline__ void async_copy16(void* lds, const void* g) {
    __builtin_amdgcn_global_load_lds((GLOBAL_AS void*)(g), (LDS_AS void*)(lds), 16, 0, 0);
}

__device__ __forceinline__ floatx4 mfma_bf16(bf16x8 a, bf16x8 b, floatx4 c) {
    return __builtin_amdgcn_mfma_f32_16x16x32_bf16(a, b, c, 0, 0, 0);
}

// fp32 -> bf16 elementwise, 4 elements/thread. n must be a multiple of 4.
__global__ void cvt_f32_bf16(const float* __restrict__ src, bf16* __restrict__ dst, int n) {
    int i = (blockIdx.x * blockDim.x + threadIdx.x) * 4;
    if (i < n) {
        float4 v = *(const float4*)(src + i);
        __align__(8) bf16 t[4];
        t[0] = __float2bfloat16(v.x);
        t[1] = __float2bfloat16(v.y);
        t[2] = __float2bfloat16(v.z);
        t[3] = __float2bfloat16(v.w);
        *(short4*)(dst + i) = *(const short4*)t;
    }
}

// C[m,n] = sum_k A[m,k] * W[n,k] + bias[n].   (bias is fp32)
// OUTF==0: C bf16 [M][N] row-major; OUTF==1: C fp32 [M][N] row-major.
template <int OUTF>
__global__ __launch_bounds__(256, 3) void gemm_bt_bias(
    const bf16* __restrict__ A, const bf16* __restrict__ W,
    const float* __restrict__ bias, void* __restrict__ Cv,
    int M, int N, int K)
{
    __shared__ __align__(16) bf16 As[128 * 32];
    __shared__ __align__(16) bf16 Ws[128 * 32];

    const int tid  = threadIdx.x;
    const int lane = tid & 63;
    const int wave = tid >> 6;
    const int quad = lane >> 4;
    const int l16  = lane & 15;
    const int wm = (wave >> 1) * 64;
    const int wn = (wave & 1) * 64;

    const int bm = blockIdx.x;
    const int bn = blockIdx.y;

    floatx4 acc[4][4];
#pragma unroll
    for (int i = 0; i < 4; ++i)
#pragma unroll
        for (int j = 0; j < 4; ++j) acc[i][j] = (floatx4){0.f, 0.f, 0.f, 0.f};

    const int srow = tid >> 2;
    const int scol = (tid & 3) * 8;
    const bf16* gA = A + (size_t)(bm * 128 + srow) * K + scol;
    const bf16* gW = W + (size_t)(bn * 128 + srow) * K + scol;
    bf16* lA0 = As + tid * 8;
    bf16* lA1 = As + 2048 + tid * 8;
    bf16* lW0 = Ws + tid * 8;
    bf16* lW1 = Ws + 2048 + tid * 8;
    const size_t skip = (size_t)64 * K;

    const int kt_n = K >> 5;
    for (int kt = 0; kt < kt_n; ++kt) {
        __syncthreads();
        const bf16* ga = gA + kt * 32;
        const bf16* gw = gW + kt * 32;
        async_copy16(lA0, ga);
        async_copy16(lA1, ga + skip);
        async_copy16(lW0, gw);
        async_copy16(lW1, gw + skip);
        __syncthreads();

        bf16x8 af[4], bfr[4];
#pragma unroll
        for (int mi = 0; mi < 4; ++mi)
            af[mi] = *(const bf16x8*)(As + (wm + mi * 16 + l16) * 32 + quad * 8);
#pragma unroll
        for (int ni = 0; ni < 4; ++ni)
            bfr[ni] = *(const bf16x8*)(Ws + (wn + ni * 16 + l16) * 32 + quad * 8);
#pragma unroll
        for (int mi = 0; mi < 4; ++mi)
#pragma unroll
            for (int ni = 0; ni < 4; ++ni)
                acc[mi][ni] = mfma_bf16(af[mi], bfr[ni], acc[mi][ni]);
    }

#pragma unroll
    for (int mi = 0; mi < 4; ++mi) {
        const int row0 = bm * 128 + wm + mi * 16 + quad * 4;
#pragma unroll
        for (int ni = 0; ni < 4; ++ni) {
            const int col = bn * 128 + wn + ni * 16 + l16;
            const float bv = bias[col];
            if (OUTF) {
                float* C = (float*)Cv;
#pragma unroll
                for (int r = 0; r < 4; ++r)
                    C[(size_t)(row0 + r) * N + col] = acc[mi][ni][r] + bv;
            } else {
                bf16* C = (bf16*)Cv;
#pragma unroll
                for (int r = 0; r < 4; ++r)
                    C[(size_t)(row0 + r) * N + col] = __float2bfloat16(acc[mi][ni][r] + bv);
            }
        }
    }
}

// Fused K+V projection. Logical N=2048: bn<8 -> K rows (k_buf row-major
// [M][1024] bf16); bn>=8 -> V rows (vt [B][1024][T] transposed bf16 store).
__global__ __launch_bounds__(256, 3) void gemm_kv(
    const bf16* __restrict__ A,
    const bf16* __restrict__ Wk, const bf16* __restrict__ Wv,
    const float* __restrict__ bk, const float* __restrict__ bv,
    bf16* __restrict__ kout, bf16* __restrict__ vt,
    int M, int K)
{
    __shared__ __align__(16) bf16 As[128 * 32];
    __shared__ __align__(16) bf16 Ws[128 * 32];

    const int tid  = threadIdx.x;
    const int lane = tid & 63;
    const int wave = tid >> 6;
    const int quad = lane >> 4;
    const int l16  = lane & 15;
    const int wm = (wave >> 1) * 64;
    const int wn = (wave & 1) * 64;

    const int bm = blockIdx.x;
    const int bn = blockIdx.y;
    const bool isK = (bn < 8);
    const int nb = isK ? bn : (bn - 8);
    const bf16* Wsel  = isK ? Wk : Wv;
    const float* bsel = isK ? bk : bv;

    floatx4 acc[4][4];
#pragma unroll
    for (int i = 0; i < 4; ++i)
#pragma unroll
        for (int j = 0; j < 4; ++j) acc[i][j] = (floatx4){0.f, 0.f, 0.f, 0.f};

    const int srow = tid >> 2;
    const int scol = (tid & 3) * 8;
    const bf16* gA = A    + (size_t)(bm * 128 + srow) * K + scol;
    const bf16* gW = Wsel + (size_t)(nb * 128 + srow) * K + scol;
    bf16* lA0 = As + tid * 8;
    bf16* lA1 = As + 2048 + tid * 8;
    bf16* lW0 = Ws + tid * 8;
    bf16* lW1 = Ws + 2048 + tid * 8;
    const size_t skip = (size_t)64 * K;

    const int kt_n = K >> 5;
    for (int kt = 0; kt < kt_n; ++kt) {
        __syncthreads();
        const bf16* ga = gA + kt * 32;
        const bf16* gw = gW + kt * 32;
        async_copy16(lA0, ga);
        async_copy16(lA1, ga + skip);
        async_copy16(lW0, gw);
        async_copy16(lW1, gw + skip);
        __syncthreads();

        bf16x8 af[4], bfr[4];
#pragma unroll
        for (int mi = 0; mi < 4; ++mi)
            af[mi] = *(const bf16x8*)(As + (wm + mi * 16 + l16) * 32 + quad * 8);
#pragma unroll
        for (int ni = 0; ni < 4; ++ni)
            bfr[ni] = *(const bf16x8*)(Ws + (wn + ni * 16 + l16) * 32 + quad * 8);
#pragma unroll
        for (int mi = 0; mi < 4; ++mi)
#pragma unroll
            for (int ni = 0; ni < 4; ++ni)
                acc[mi][ni] = mfma_bf16(af[mi], bfr[ni], acc[mi][ni]);
    }

#pragma unroll
    for (int mi = 0; mi < 4; ++mi) {
        const int row0 = bm * 128 + wm + mi * 16 + quad * 4;
#pragma unroll
        for (int ni = 0; ni < 4; ++ni) {
            const int col = nb * 128 + wn + ni * 16 + l16;
            const float bvv = bsel[col];
            if (isK) {
#pragma unroll
                for (int r = 0; r < 4; ++r)
                    kout[(size_t)(row0 + r) * 1024 + col] = __float2bfloat16(acc[mi][ni][r] + bvv);
            } else {
                __align__(8) bf16 tmp[4];
#pragma unroll
                for (int r = 0; r < 4; ++r) tmp[r] = __float2bfloat16(acc[mi][ni][r] + bvv);
                const int b  = row0 >> 11;      // T = 2048
                const int t0 = row0 & 2047;
                bf16* dst = vt + ((size_t)(b * 1024 + col)) * 2048 + t0;
                *(short4*)dst = *(const short4*)tmp;
            }
        }
    }
}

// Flash attention, causal, balanced q-tile pairing.
// Block (qi, bh) handles q-tiles qtB=31-qi (large) and qtA=qi (small) of head
// bh. Every block computes exactly 33 tile-units; K/V loads for the small
// tile are a subset of the large tile's, so each loaded K/V tile feeds 2x
// MFMA work in the overlapped range. Cooperative LDS staging only (no
// register pipeline -- round-3's reg staging spilled to scratch: 470MB writes).
__global__ __launch_bounds__(256, 2) void attn_fwd(
    const bf16* __restrict__ qb, const bf16* __restrict__ kb,
    const bf16* __restrict__ vtb, bf16* __restrict__ ob)
{
    constexpr int T  = 2048;
    constexpr int DQ = 4096;
    constexpr int DK = 1024;

    __shared__ __align__(16) bf16 Qs[128][136];  // rows 0-63: tile B, 64-127: tile A
    __shared__ __align__(16) bf16 Ks[64][136];
    __shared__ __align__(16) bf16 Vt[128][72];   // [d][s]
    __shared__ __align__(16) bf16 Ps[4][16][72]; // per-wave P tile

    const int tid  = threadIdx.x;
    const int lane = tid & 63;
    const int wave = tid >> 6;
    const int quad = lane >> 4;
    const int l16  = lane & 15;

    const int qi = blockIdx.x;    // 0..15
    const int bh = blockIdx.y;
    const int b  = bh >> 5;
    const int h  = bh & 31;
    const int g  = h >> 2;        // GROUP = 4
    const int qtB = 31 - qi;      // large tile
    const int qtA = qi;           // small tile
    const int q0B = qtB * 64;
    const int q0A = qtA * 64;
    const int qw = wave * 16;

    const bf16* Qg = qb  + (size_t)b * T * DQ + (size_t)h * 128;
    const bf16* Kg = kb  + (size_t)b * T * DK + (size_t)g * 128;
    const bf16* Vg = vtb + ((size_t)b * DK + g * 128) * T;
    bf16*       Og = ob  + (size_t)b * T * DQ + (size_t)h * 128;

#pragma unroll
    for (int it = 0; it < 8; ++it) {
        int idx = it * 256 + tid;
        int r = idx >> 4, c = (idx & 15) * 8;
        int grow = (r < 64) ? (q0B + r) : (q0A + r - 64);
        *(int4*)&Qs[r][c] = *(const int4*)(Qg + (size_t)grow * DQ + c);
    }

    floatx4 oacc[2][8];
#pragma unroll
    for (int t = 0; t < 2; ++t)
#pragma unroll
        for (int i = 0; i < 8; ++i) oacc[t][i] = (floatx4){0.f, 0.f, 0.f, 0.f};
    float m_run[2][4], l_run[2][4];
#pragma unroll
    for (int t = 0; t < 2; ++t)
#pragma unroll
        for (int r = 0; r < 4; ++r) { m_run[t][r] = -1e30f; l_run[t][r] = 0.f; }

    const float scale = 0.08838834764831845f;  // 1/sqrt(128)

    for (int st = 0; st <= qtB; ++st) {
        const int s0 = st * 64;
        __syncthreads();
#pragma unroll
        for (int it = 0; it < 4; ++it) {
            int idx = it * 256 + tid;
            int r = idx >> 4, c = (idx & 15) * 8;
            *(int4*)&Ks[r][c] = *(const int4*)(Kg + (size_t)(s0 + r) * DK + c);
        }
#pragma unroll
        for (int it = 0; it < 4; ++it) {
            int idx = it * 256 + tid;
            int r = idx >> 3, c = (idx & 7) * 8;
            *(int4*)&Vt[r][c] = *(const int4*)(Vg + (size_t)r * T + s0 + c);
        }
        __syncthreads();

        const int ntile = (st <= qtA) ? 2 : 1;
#pragma unroll
        for (int t = 0; t < 2; ++t) {
            if (t >= ntile) break;
            const int q0t  = t ? q0A : q0B;
            const int qt_t = t ? qtA : qtB;
            const int rowbase = t * 64;

            // S[16q][64s] for this tile
            floatx4 sacc[4];
#pragma unroll
            for (int i = 0; i < 4; ++i) sacc[i] = (floatx4){0.f, 0.f, 0.f, 0.f};
#pragma unroll
            for (int kk = 0; kk < 4; ++kk) {
                bf16x8 aq = *(const bf16x8*)&Qs[rowbase + qw + l16][kk * 32 + quad * 8];
#pragma unroll
                for (int ni = 0; ni < 4; ++ni) {
                    bf16x8 bk8 = *(const bf16x8*)&Ks[ni * 16 + l16][kk * 32 + quad * 8];
                    sacc[ni] = mfma_bf16(aq, bk8, sacc[ni]);
                }
            }

            const bool diag = (st == qt_t);
#pragma unroll
            for (int r = 0; r < 4; ++r) {
                const int qg = q0t + qw + quad * 4 + r;   // C/D row = quad*4+reg
                float sv[4];
#pragma unroll
                for (int ni = 0; ni < 4; ++ni) {
                    float x = sacc[ni][r] * scale;
                    if (diag && (s0 + ni * 16 + l16) > qg) x = -1e30f;
                    sv[ni] = x;
                }
                float mx = fmaxf(fmaxf(sv[0], sv[1]), fmaxf(sv[2], sv[3]));
                mx = fmaxf(mx, __shfl_xor(mx, 1, 64));
                mx = fmaxf(mx, __shfl_xor(mx, 2, 64));
                mx = fmaxf(mx, __shfl_xor(mx, 4, 64));
                mx = fmaxf(mx, __shfl_xor(mx, 8, 64));
                const float mnew  = fmaxf(m_run[t][r], mx);
                const float alpha = __expf(m_run[t][r] - mnew);
                float ssum = 0.f;
#pragma unroll
                for (int ni = 0; ni < 4; ++ni) {
                    float p = __expf(sv[ni] - mnew);
                    ssum += p;
                    Ps[wave][quad * 4 + r][ni * 16 + l16] = __float2bfloat16(p);
                }
                ssum += __shfl_xor(ssum, 1, 64);
                ssum += __shfl_xor(ssum, 2, 64);
                ssum += __shfl_xor(ssum, 4, 64);
                ssum += __shfl_xor(ssum, 8, 64);
                l_run[t][r] = l_run[t][r] * alpha + ssum;
                m_run[t][r] = mnew;
#pragma unroll
                for (int db = 0; db < 8; ++db) oacc[t][db][r] *= alpha;
            }
            asm volatile("s_waitcnt lgkmcnt(0)" ::: "memory");

            // O += P @ V
#pragma unroll
            for (int kk = 0; kk < 2; ++kk) {
                bf16x8 ap = *(const bf16x8*)&Ps[wave][l16][kk * 32 + quad * 8];
#pragma unroll
                for (int db = 0; db < 8; ++db) {
                    bf16x8 bv8 = *(const bf16x8*)&Vt[db * 16 + l16][kk * 32 + quad * 8];
                    oacc[t][db] = mfma_bf16(ap, bv8, oacc[t][db]);
                }
            }
        }
    }

#pragma unroll
    for (int t = 0; t < 2; ++t) {
        const int q0t = t ? q0A : q0B;
#pragma unroll
        for (int r = 0; r < 4; ++r) {
            const float inv = 1.0f / l_run[t][r];
            const int qg = q0t + qw + quad * 4 + r;
#pragma unroll
            for (int db = 0; db < 8; ++db)
                Og[(size_t)qg * DQ + db * 16 + l16] = __float2bfloat16(oacc[t][db][r] * inv);
        }
    }
}

extern "C" void kernel_launch(void* const* d_in, const int* in_sizes, int n_in,
                              void* d_out, int out_size, void* d_ws, size_t ws_size,
                              hipStream_t stream)
{
    const float* hs = (const float*)d_in[0];
    const float* Wq = (const float*)d_in[1];
    const float* bq = (const float*)d_in[2];
    const float* Wk = (const float*)d_in[3];
    const float* bk = (const float*)d_in[4];
    const float* Wv = (const float*)d_in[5];
    const float* bv = (const float*)d_in[6];
    const float* Wo = (const float*)d_in[7];
    const float* bo = (const float*)d_in[8];
    float* out = (float*)d_out;

    const int M  = 4096;         // B*T tokens
    const int D  = 4096;
    const int DK = 1024;         // G*d
    const size_t SZ_D  = (size_t)M * D;
    const size_t SZ_K  = (size_t)M * DK;

    bf16* hsb  = (bf16*)d_ws;            // [M][D]
    bf16* Wqb  = hsb  + SZ_D;            // [D][D]
    bf16* Wkb  = Wqb  + SZ_D;            // [DK][D]
    bf16* Wvb  = Wkb  + SZ_K;            // [DK][D]
    bf16* Wob  = Wvb  + SZ_K;            // [D][D]
    bf16* q_buf = Wob + SZ_D;            // [M][D]
    bf16* k_buf = q_buf + SZ_D;          // [M][DK]
    bf16* vt_buf = Wqb;                  // ALIAS: Wq consumed before KV-gemm writes vt
    bf16* o_buf  = hsb;                  // ALIAS: hs consumed before attn writes o

    dim3 blk(256);
    const int CB = 256;
    cvt_f32_bf16<<<(int)(SZ_D / 4 + CB - 1) / CB, CB, 0, stream>>>(hs, hsb, (int)SZ_D);
    cvt_f32_bf16<<<(int)(SZ_D / 4 + CB - 1) / CB, CB, 0, stream>>>(Wq, Wqb, (int)SZ_D);
    cvt_f32_bf16<<<(int)(SZ_K / 4 + CB - 1) / CB, CB, 0, stream>>>(Wk, Wkb, (int)SZ_K);
    cvt_f32_bf16<<<(int)(SZ_K / 4 + CB - 1) / CB, CB, 0, stream>>>(Wv, Wvb, (int)SZ_K);
    cvt_f32_bf16<<<(int)(SZ_D / 4 + CB - 1) / CB, CB, 0, stream>>>(Wo, Wob, (int)SZ_D);

    gemm_bt_bias<0><<<dim3(M / 128, D / 128), blk, 0, stream>>>(hsb, Wqb, bq, q_buf, M, D, D);
    gemm_kv<<<dim3(M / 128, 16), blk, 0, stream>>>(hsb, Wkb, Wvb, bk, bv, k_buf, vt_buf, M, D);
    attn_fwd<<<dim3(16, 64), blk, 0, stream>>>(q_buf, k_buf, vt_buf, o_buf);
    gemm_bt_bias<1><<<dim3(M / 128, D / 128), blk, 0, stream>>>(o_buf, Wob, bo, out, M, D, D);
}